// Round 15
// baseline (487.014 us; speedup 1.0000x reference)
//
#include <hip/hip_runtime.h>

#define NB   4
#define SEQ  1024
#define MD   1024
#define NH   16
#define HD   64
#define FF   4096
#define NK   (NB*SEQ)
#define EPSF 1e-5f
#define QS   3072          // fused QKV row stride (bf16 elems)

typedef short short8 __attribute__((ext_vector_type(8)));
typedef float f32x4  __attribute__((ext_vector_type(4)));
typedef unsigned short u16;
typedef unsigned int u32;

__device__ __forceinline__ u16 f2bf(float x) {
    union { float f; unsigned u; } v; v.f = x;
    unsigned r = v.u + 0x7FFF + ((v.u >> 16) & 1);
    return (u16)(r >> 16);
}
__device__ __forceinline__ u16 f2bf_trunc(float x) {   // positive values
    union { float f; unsigned u; } v; v.f = x;
    return (u16)(v.u >> 16);
}
__device__ __forceinline__ float bf2f(u16 x) {
    union { unsigned u; float f; } v; v.u = ((unsigned)x) << 16;
    return v.f;
}
__device__ __forceinline__ void gload_lds16(const void* g, void* l) {
    __builtin_amdgcn_global_load_lds(
        (const __attribute__((address_space(1))) unsigned int*)g,
        (__attribute__((address_space(3))) unsigned int*)l,
        16, 0, 0);
}
__device__ __forceinline__ void gload_lds4(const void* g, void* l) {
    __builtin_amdgcn_global_load_lds(
        (const __attribute__((address_space(1))) unsigned int*)g,
        (__attribute__((address_space(3))) unsigned int*)l,
        4, 0, 0);
}

// ---------------------------------------------------------------------------
// dec+enc fp32 -> bf16. Grid (4096, 2).
// ---------------------------------------------------------------------------
__global__ __launch_bounds__(256) void conv_bf16(const float* __restrict__ s0,
                                                 const float* __restrict__ s1,
                                                 u16* __restrict__ d0,
                                                 u16* __restrict__ d1) {
    const float* S = blockIdx.y ? s1 : s0;
    u16* D = blockIdx.y ? d1 : d0;
    const int i = blockIdx.x * 256 + threadIdx.x;
    float4 v = ((const float4*)S)[i];
    ushort4 o;
    o.x = f2bf(v.x); o.y = f2bf(v.y); o.z = f2bf(v.z); o.w = f2bf(v.w);
    ((ushort4*)D)[i] = o;
}

// ---------------------------------------------------------------------------
// Mask tile precompute for 128x128 tiles. Grid (8,8,4), blk 256.
// ---------------------------------------------------------------------------
__global__ __launch_bounds__(256) void mask_tiles(const int* __restrict__ mask,
                                                  int* __restrict__ cls,
                                                  u32* __restrict__ bits) {
    const int jt = blockIdx.x, qt = blockIdx.y, n = blockIdx.z;
    const int t = threadIdx.x;
    const int r = t >> 1, h2 = (t & 1) * 2;
    u32 bb[2];
#pragma unroll
    for (int sg = 0; sg < 2; ++sg) {
        const int* mp = &mask[((size_t)n * SEQ + qt * 128 + r) * SEQ + jt * 128 + (h2 + sg) * 32];
        u32 b = 0;
#pragma unroll
        for (int k = 0; k < 8; ++k) {
            int4 v = *(const int4*)(mp + k * 4);
            b |= (v.x ? 1u : 0u) << (k * 4 + 0);
            b |= (v.y ? 1u : 0u) << (k * 4 + 1);
            b |= (v.z ? 1u : 0u) << (k * 4 + 2);
            b |= (v.w ? 1u : 0u) << (k * 4 + 3);
        }
        bb[sg] = b;
    }
    const int tile = (n * 8 + qt) * 8 + jt;
    bits[((size_t)tile * 128 + r) * 4 + h2]     = bb[0];
    bits[((size_t)tile * 128 + r) * 4 + h2 + 1] = bb[1];
    const int nfull  = __syncthreads_count(bb[0] == 0xFFFFFFFFu && bb[1] == 0xFFFFFFFFu);
    const int nempty = __syncthreads_count(bb[0] == 0u && bb[1] == 0u);
    if (t == 0) cls[tile] = (nfull == 256) ? 2 : ((nempty == 256) ? 0 : 1);
}

// ---------------------------------------------------------------------------
// QKV weight repack (6 heads-major weights -> fused transposed buffers).
// ---------------------------------------------------------------------------
struct QkvArgs { const float* src[6]; u16* dst[6]; };

__global__ __launch_bounds__(256) void repack_qkv(QkvArgs a) {
    const int m0 = blockIdx.x * 64;
    const int h  = blockIdx.y;
    const int w  = blockIdx.z;
    const float* W = a.src[w];
    u16* BT = a.dst[w];
    const int t = threadIdx.x;
    __shared__ u16 Ts[64][72];

    const int r = t >> 4, c4 = (t & 15) * 4;
#pragma unroll
    for (int p = 0; p < 4; ++p) {
        const int row = r + p * 16;
        float4 v = *(const float4*)&W[((size_t)h * 1024 + m0 + row) * 64 + c4];
        Ts[row][c4] = f2bf(v.x); Ts[row][c4 + 1] = f2bf(v.y);
        Ts[row][c4 + 2] = f2bf(v.z); Ts[row][c4 + 3] = f2bf(v.w);
    }
    __syncthreads();
    const int d = t >> 2, j0 = (t & 3) * 16;
#pragma unroll
    for (int p = 0; p < 4; ++p) {
        ushort4 o;
        o.x = Ts[j0 + p * 4 + 0][d]; o.y = Ts[j0 + p * 4 + 1][d];
        o.z = Ts[j0 + p * 4 + 2][d]; o.w = Ts[j0 + p * 4 + 3][d];
        *(ushort4*)&BT[((size_t)h * 64 + d) * 1024 + m0 + j0 + p * 4] = o;
    }
}

// ---------------------------------------------------------------------------
// Flat weight repacks via descriptors. Grid (16,16,10).
// ---------------------------------------------------------------------------
struct FD { const float* src; int ss; u16* dst; int ds; };
struct FlatArgs { FD d[10]; };

__global__ __launch_bounds__(256) void repack_flat(FlatArgs fa) {
    FD u = fa.d[blockIdx.z];
    const int r0 = blockIdx.x * 64;
    const int c0 = blockIdx.y * 64;
    const int t  = threadIdx.x;
    __shared__ u16 Ts[64][72];

    const int r = t >> 4, c4 = (t & 15) * 4;
#pragma unroll
    for (int p = 0; p < 4; ++p) {
        const int row = r + p * 16;
        float4 v = *(const float4*)&u.src[(size_t)(r0 + row) * u.ss + c0 + c4];
        Ts[row][c4] = f2bf(v.x); Ts[row][c4 + 1] = f2bf(v.y);
        Ts[row][c4 + 2] = f2bf(v.z); Ts[row][c4 + 3] = f2bf(v.w);
    }
    __syncthreads();
    const int d = t >> 2, j0 = (t & 3) * 16;
#pragma unroll
    for (int p = 0; p < 4; ++p) {
        ushort4 o;
        o.x = Ts[j0 + p * 4 + 0][d]; o.y = Ts[j0 + p * 4 + 1][d];
        o.z = Ts[j0 + p * 4 + 2][d]; o.w = Ts[j0 + p * 4 + 3][d];
        *(ushort4*)&u.dst[(size_t)(c0 + d) * u.ds + r0 + j0 + p * 4] = o;
    }
}

// ---------------------------------------------------------------------------
// gemm_256: 256x256 block tile, 8 waves (2M x 4N), per-wave 128x64 output.
// K-slice ring pipeline, counted vmcnt(8). (Proven R5.)
// VT epilogue via LDS transpose (R11). CT (R13): C^T shfl-packed 64 B-run
// stores (FFN1). FROZEN this round.
// ---------------------------------------------------------------------------
template<int RELU, int BIAS3, int VT, int CT>
__global__ __launch_bounds__(512, 2) void gemm_256(const u16* __restrict__ A,
                                                   const u16* __restrict__ A2,
                                                   int Astride,
                                                   const u16* __restrict__ BT,
                                                   int Bstride,
                                                   const float* __restrict__ b0,
                                                   const float* __restrict__ b1p,
                                                   const float* __restrict__ b2p,
                                                   u16* __restrict__ Cout,
                                                   u16* __restrict__ VtOut,
                                                   int Kd, int Nd) {
    const u32 gx = gridDim.x, gy = gridDim.y;
    const u32 T  = gx * gy;
    const u32 dd = blockIdx.y * gx + blockIdx.x;
    const u32 wid = (dd & 7) * (T >> 3) + (dd >> 3);
    const int nt = wid % gx;
    const int mt = wid / gx;

    const int t  = threadIdx.x;
    const int wave = t >> 6, lane = t & 63;
    const int q = lane >> 4, l16 = lane & 15;
    const int wm = wave >> 2, wn = wave & 3;       // 2M x 4N
    const int srow = lane >> 2, schk = lane & 3;

    __shared__ __align__(16) u16 As[4][256 * 32];  // 64 KB
    __shared__ __align__(16) u16 Bs[4][256 * 32];  // 64 KB

    const int row0 = mt * 256, col0 = nt * 256;
    const u16* Ause = (col0 < 1024) ? A : A2;
    const int ns = Kd / 32;

    f32x4 acc[8][4];
#pragma unroll
    for (int r = 0; r < 8; ++r)
#pragma unroll
        for (int c = 0; c < 4; ++c) acc[r][c] = (f32x4)0.0f;

    auto stage = [&](int ss) {
        const int k0 = ss * 32;
        u16* Ad = &As[ss & 3][0];
        u16* Bd = &Bs[ss & 3][0];
#pragma unroll
        for (int p = 0; p < 2; ++p) {
            const int rg = wave * 32 + p * 16 + srow;
            const int gc = schk ^ ((rg >> 1) & 3);
            gload_lds16(Ause + (size_t)(row0 + rg) * Astride + k0 + gc * 8,
                        Ad + (wave * 32 + p * 16) * 32);
            gload_lds16(BT + (size_t)(col0 + rg) * Bstride + k0 + gc * 8,
                        Bd + (wave * 32 + p * 16) * 32);
        }
    };

    stage(0);
    if (ns > 1) stage(1);
    if (ns > 2) stage(2);

    for (int s = 0; s < ns; ++s) {
        const int lead = ns - 1 - s;
        if (lead >= 2)      { asm volatile("s_waitcnt vmcnt(8)" ::: "memory"); }
        else if (lead == 1) { asm volatile("s_waitcnt vmcnt(4)" ::: "memory"); }
        else                { asm volatile("s_waitcnt vmcnt(0)" ::: "memory"); }
        __builtin_amdgcn_sched_barrier(0);
        __builtin_amdgcn_s_barrier();
        __builtin_amdgcn_sched_barrier(0);

        const u16* Ab = &As[s & 3][0];
        const u16* Bb = &Bs[s & 3][0];
        short8 af[8], bf[4];
#pragma unroll
        for (int fr = 0; fr < 8; ++fr) {
            const int ar = wm * 128 + fr * 16 + l16;
            af[fr] = *(const short8*)&Ab[ar * 32 + ((q ^ ((ar >> 1) & 3)) * 8)];
        }
#pragma unroll
        for (int fc = 0; fc < 4; ++fc) {
            const int br = wn * 64 + fc * 16 + l16;
            bf[fc] = *(const short8*)&Bb[br * 32 + ((q ^ ((br >> 1) & 3)) * 8)];
        }

        if (s + 3 < ns) stage(s + 3);

        __builtin_amdgcn_s_setprio(1);
#pragma unroll
        for (int fr = 0; fr < 8; ++fr)
#pragma unroll
            for (int fc = 0; fc < 4; ++fc) {
                if (CT)
                    acc[fr][fc] = __builtin_amdgcn_mfma_f32_16x16x32_bf16(bf[fc], af[fr], acc[fr][fc], 0, 0, 0);
                else
                    acc[fr][fc] = __builtin_amdgcn_mfma_f32_16x16x32_bf16(af[fr], bf[fc], acc[fr][fc], 0, 0, 0);
            }
        __builtin_amdgcn_s_setprio(0);
        __builtin_amdgcn_sched_barrier(0);
    }

    if (VT && !CT && col0 >= 2048) {
        // ---- coalesced Vt epilogue via LDS transpose ----
        __builtin_amdgcn_s_barrier();          // all waves done reading As/Bs
        u16* LT = (wn < 2) ? (&As[0][0] + wn * 16384) : (&Bs[0][0] + (wn - 2) * 16384);
#pragma unroll
        for (int fc = 0; fc < 4; ++fc) {
            const int d = fc * 16 + l16;
            const float bb = b2p[(col0 + wn * 64 + d) & 1023];
#pragma unroll
            for (int fr = 0; fr < 8; ++fr) {
                const int kb  = wm * 32 + fr * 4 + q;   // 8B k-chunk index
                const int kbs = kb ^ l16;               // bank spread (bijective per d)
                ushort4 o;
                o.x = f2bf(acc[fr][fc][0] + bb);
                o.y = f2bf(acc[fr][fc][1] + bb);
                o.z = f2bf(acc[fr][fc][2] + bb);
                o.w = f2bf(acc[fr][fc][3] + bb);
                *(ushort4*)&LT[d * 256 + kbs * 4] = o;
            }
        }
        __builtin_amdgcn_s_barrier();
        const int nn = row0 >> 10, k0 = row0 & 1023;
        const int hbase = (col0 - 2048) >> 6;
#pragma unroll
        for (int it = 0; it < 16; ++it) {
            const int c  = it * 512 + t;
            const int hh = c >> 11;
            const int r  = c & 2047;
            const int d  = r >> 5;
            const int kc = r & 31;                 // 8-elem k chunk
            const u16* LR = (hh < 2) ? (&As[0][0] + hh * 16384) : (&Bs[0][0] + (hh - 2) * 16384);
            const int x   = d & 15;
            const int kb0 = (kc * 2) ^ x;
            const int kb1 = kb0 ^ 1;
            uint2 lo = *(const uint2*)&LR[d * 256 + kb0 * 4];
            uint2 hi = *(const uint2*)&LR[d * 256 + kb1 * 4];
            uint4 o4; o4.x = lo.x; o4.y = lo.y; o4.z = hi.x; o4.w = hi.y;
            *(uint4*)&VtOut[((size_t)(nn * 16 + hbase + hh) * 64 + d) * 1024 + k0 + kc * 8] = o4;
        }
        return;
    }

    if (CT) {
        // ---- C^T epilogue: shfl-pack to 64 B-per-row uint4 stores ----
#pragma unroll
        for (int p2 = 0; p2 < 2; ++p2) {
            const int fcA = p2 * 2, fcB = p2 * 2 + 1;
            const int colbase = col0 + wn * 64 + fcA * 16;
            float4 bbA, bbB;
            if (BIAS3) {
                bbA = *(const float4*)&b0[(colbase + q * 4) & 1023];
                bbB = *(const float4*)&b0[(colbase + 16 + q * 4) & 1023];
            } else {
                bbA = *(const float4*)&b0[colbase + q * 4];
                bbB = *(const float4*)&b0[colbase + 16 + q * 4];
            }
#pragma unroll
            for (int fr = 0; fr < 8; ++fr) {
                float a0 = acc[fr][fcA][0] + bbA.x;
                float a1 = acc[fr][fcA][1] + bbA.y;
                float a2 = acc[fr][fcA][2] + bbA.z;
                float a3 = acc[fr][fcA][3] + bbA.w;
                float b0v = acc[fr][fcB][0] + bbB.x;
                float b1v = acc[fr][fcB][1] + bbB.y;
                float b2v = acc[fr][fcB][2] + bbB.z;
                float b3v = acc[fr][fcB][3] + bbB.w;
                if (RELU) {
                    a0 = fmaxf(a0, 0.0f); a1 = fmaxf(a1, 0.0f);
                    a2 = fmaxf(a2, 0.0f); a3 = fmaxf(a3, 0.0f);
                    b0v = fmaxf(b0v, 0.0f); b1v = fmaxf(b1v, 0.0f);
                    b2v = fmaxf(b2v, 0.0f); b3v = fmaxf(b3v, 0.0f);
                }
                u32 u0lo = (u32)f2bf(a0) | ((u32)f2bf(a1) << 16);
                u32 u0hi = (u32)f2bf(a2) | ((u32)f2bf(a3) << 16);
                u32 u1lo = (u32)f2bf(b0v) | ((u32)f2bf(b1v) << 16);
                u32 u1hi = (u32)f2bf(b2v) | ((u32)f2bf(b3v) << 16);
                u32 x0lo = (u32)__shfl_xor((int)u0lo, 16);
                u32 x0hi = (u32)__shfl_xor((int)u0hi, 16);
                u32 x1lo = (u32)__shfl_xor((int)u1lo, 16);
                u32 x1hi = (u32)__shfl_xor((int)u1hi, 16);
                uint4 o;
                if (q & 1) { o.x = x1lo; o.y = x1hi; o.z = u1lo; o.w = u1hi; }
                else       { o.x = u0lo; o.y = u0hi; o.z = x0lo; o.w = x0hi; }
                const int coloff = (q & 1) * 16 + (q & 2) * 4;
                const int row = row0 + wm * 128 + fr * 16 + l16;
                *(uint4*)&Cout[(size_t)row * Nd + colbase + coloff] = o;
            }
        }
        return;
    }

#pragma unroll
    for (int fc = 0; fc < 4; ++fc) {
        const int col = col0 + wn * 64 + fc * 16 + l16;
        float bb;
        if (BIAS3) {
            const int sec = col >> 10;
            const float* bp = sec == 0 ? b0 : (sec == 1 ? b1p : b2p);
            bb = bp[col & 1023];
        } else {
            bb = b0[col];
        }
#pragma unroll
        for (int fr = 0; fr < 8; ++fr) {
#pragma unroll
            for (int reg = 0; reg < 4; ++reg) {
                const int row = row0 + wm * 128 + fr * 16 + q * 4 + reg;
                float v = acc[fr][fc][reg] + bb;
                if (RELU) v = fmaxf(v, 0.0f);
                Cout[(size_t)row * Nd + col] = f2bf(v);
            }
        }
    }
}

// ---------------------------------------------------------------------------
// gemm_sk: split-K deep-pipeline GEMM for the N=1024 sites.
// R15: ring 4 -> 3 slots (LDS 96 -> 72 KB) => 2 blocks/CU (16 waves) for
// latency cover; pipeline depth 2, counted vmcnt(3) in-loop.
// Ledger: FIFO retirement per wave -> vmcnt(3) at iter s retires exactly
// slice s (s+1's 3 loads stay airborne); slot (s+2)%3 == (s-1)%3 whose
// readers finished before each wave crossed barrier(s) -> WAR safe; tail
// drains vmcnt(0). 256x128 tile, 8 waves (4M x 2N), acc[4][4].
// ---------------------------------------------------------------------------
__global__ __launch_bounds__(512, 2) void gemm_sk(const u16* __restrict__ A,
                                                  int Astride,
                                                  const u16* __restrict__ BT,
                                                  int Bstride,
                                                  float* __restrict__ P0,
                                                  float* __restrict__ P1,
                                                  int Kd, int Nd) {
    const u32 gx = gridDim.x, gy = gridDim.y;
    const u32 T  = gx * gy * gridDim.z;
    const u32 dd = (blockIdx.z * gy + blockIdx.y) * gx + blockIdx.x;
    const u32 wid = (dd & 7) * (T >> 3) + (dd >> 3);
    const int nt = wid % gx;
    const int mt = (wid / gx) % gy;
    const int zz = wid / (gx * gy);

    const int t  = threadIdx.x;
    const int wave = t >> 6, lane = t & 63;
    const int q = lane >> 4, l16 = lane & 15;
    const int wm = wave >> 1, wn = wave & 1;       // 4M x 2N
    const int srow = lane >> 2, schk = lane & 3;

    __shared__ __align__(16) u16 As[3][256 * 32];  // 48 KB
    __shared__ __align__(16) u16 Bs[3][128 * 32];  // 24 KB

    const int row0 = mt * 256, col0 = nt * 128;
    const int kBase = zz * Kd;
    const int ns = Kd / 32;

    f32x4 acc[4][4];
#pragma unroll
    for (int r = 0; r < 4; ++r)
#pragma unroll
        for (int c = 0; c < 4; ++c) acc[r][c] = (f32x4)0.0f;

    auto stage = [&](int ss) {
        const int k0 = kBase + ss * 32;
        const int sl = ss % 3;
        u16* Ad = &As[sl][0];
        u16* Bd = &Bs[sl][0];
#pragma unroll
        for (int p = 0; p < 2; ++p) {
            const int rg = wave * 32 + p * 16 + srow;
            const int gc = schk ^ ((rg >> 1) & 3);
            gload_lds16(A + (size_t)(row0 + rg) * Astride + k0 + gc * 8,
                        Ad + (wave * 32 + p * 16) * 32);
        }
        {
            const int rb = wave * 16 + srow;
            const int gc = schk ^ ((rb >> 1) & 3);
            gload_lds16(BT + (size_t)(col0 + rb) * Bstride + k0 + gc * 8,
                        Bd + (wave * 16) * 32);
        }
    };

    stage(0);
    if (ns > 1) stage(1);

    const int pb = (q ^ ((l16 >> 1) & 3)) * 8;

    for (int s = 0; s < ns; ++s) {
        const int lead = ns - 1 - s;
        if (lead >= 1) { asm volatile("s_waitcnt vmcnt(3)" ::: "memory"); }
        else           { asm volatile("s_waitcnt vmcnt(0)" ::: "memory"); }
        __builtin_amdgcn_sched_barrier(0);
        __builtin_amdgcn_s_barrier();
        __builtin_amdgcn_sched_barrier(0);

        const int sl = s % 3;
        const u16* Ab = &As[sl][0];
        const u16* Bb = &Bs[sl][0];
        short8 af[4], bf[4];
#pragma unroll
        for (int r = 0; r < 4; ++r)
            af[r] = *(const short8*)&Ab[(wm * 64 + r * 16 + l16) * 32 + pb];
#pragma unroll
        for (int c = 0; c < 4; ++c)
            bf[c] = *(const short8*)&Bb[(wn * 64 + c * 16 + l16) * 32 + pb];

        if (s + 2 < ns) stage(s + 2);

        __builtin_amdgcn_s_setprio(1);
#pragma unroll
        for (int r = 0; r < 4; ++r)
#pragma unroll
            for (int c = 0; c < 4; ++c)
                acc[r][c] = __builtin_amdgcn_mfma_f32_16x16x32_bf16(af[r], bf[c], acc[r][c], 0, 0, 0);
        __builtin_amdgcn_s_setprio(0);
        __builtin_amdgcn_sched_barrier(0);
    }

    float* Pout = zz ? P1 : P0;
#pragma unroll
    for (int c = 0; c < 4; ++c) {
        const int col = col0 + wn * 64 + c * 16 + l16;
#pragma unroll
        for (int r = 0; r < 4; ++r) {
#pragma unroll
            for (int reg = 0; reg < 4; ++reg) {
                const int row = row0 + wm * 64 + r * 16 + q * 4 + reg;
                Pout[(size_t)row * Nd + col] = acc[r][c][reg];
            }
        }
    }
}

// ---------------------------------------------------------------------------
// MFMA flash attention v9 (R12-proven): v8 + shared LDS reads across the two
// q-subtiles. FROZEN this round.
// ---------------------------------------------------------------------------
#define PSTR 140

__global__ __launch_bounds__(512, 2) void attn_mfma(const u16* __restrict__ QKV,
                                                    const u16* __restrict__ Vt,
                                                    const int* __restrict__ cls,
                                                    const u32* __restrict__ bits,
                                                    u16* __restrict__ Yout) {
    const u32 T  = gridDim.x * gridDim.y * gridDim.z;   // 256
    const u32 dd = (blockIdx.z * gridDim.y + blockIdx.y) * gridDim.x + blockIdx.x;
    const u32 wid = (dd & 7) * (T >> 3) + (dd >> 3);
    const int qt = wid % gridDim.x;                      // 256-q tile
    const int h  = (wid / gridDim.x) % gridDim.y;
    const int n  = wid / (gridDim.x * gridDim.y);

    const int t    = threadIdx.x;
    const int wave = t >> 6;
    const int lane = t & 63;
    const int quad = lane >> 4;
    const int l16  = lane & 15;
    const int half = wave >> 2;        // 0: q-rows 0-127, 1: 128-255
    const int w4   = wave & 3;

    __shared__ __align__(16) u16 Ks2[2][128 * 64];   // 32 KB
    __shared__ __align__(16) u16 Vs2[2][64 * 128];   // 32 KB
    __shared__ __align__(16) u16 Ps[8][32 * PSTR];   // 70 KB (wave-private, both s)
    __shared__ u32 Mb[2][256][4];                    // 8 KB

    const int bh = n * NH + h;
    const int i0 = qt * 256;
    const int q128a = qt * 2, q128b = qt * 2 + 1;

    // Q fragments (2 q-subtiles of 16 rows per wave), pre-scaled by
    // 0.125*log2e. Used as the B operand of the swapped QK^T.
    short8 qf[2][2];
#pragma unroll
    for (int s = 0; s < 2; ++s) {
        const u16* qrow = QKV + ((size_t)n * SEQ + i0 + half * 128 + s * 64 + w4 * 16 + l16) * QS + h * 64 + quad * 8;
        short8 a = *(const short8*)(qrow);
        short8 b = *(const short8*)(qrow + 32);
#pragma unroll
        for (int j = 0; j < 8; ++j) {
            qf[s][0][j] = (short)f2bf(bf2f((u16)a[j]) * 0.18033688f);
            qf[s][1][j] = (short)f2bf(bf2f((u16)b[j]) * 0.18033688f);
        }
    }

    f32x4 O[2][4];
#pragma unroll
    for (int s = 0; s < 2; ++s)
#pragma unroll
        for (int d = 0; d < 4; ++d) O[s][d] = (f32x4)0.0f;
    float lq[2] = {0.0f, 0.0f};        // per-lane query (l16) running sum

    const int krow = lane >> 3, kblk = lane & 7;
    const int vrow = lane >> 4, vblk = lane & 15;
    const int x7 = l16 & 7;
    const int hasb = bits != nullptr;

    auto stage = [&](int jt, int b) {
#pragma unroll
        for (int p = 0; p < 2; ++p) {
            const int rr = wave * 16 + p * 8 + krow;
            const int kb = kblk ^ (rr & 7);
            gload_lds16(QKV + ((size_t)n * SEQ + jt * 128 + rr) * QS + 1024 + h * 64 + kb * 8,
                        &Ks2[b][(wave * 16 + p * 8) * 64]);
        }
#pragma unroll
        for (int p = 0; p < 2; ++p) {
            const int rr = wave * 8 + p * 4 + vrow;
            const int kb = vblk ^ (rr & 15);
            gload_lds16(Vt + ((size_t)bh * HD + rr) * SEQ + jt * 128 + kb * 8,
                        &Vs2[b][(wave * 8 + p * 4) * 128]);
        }
    };
    auto stage_mask = [&](int jt, int mb) {
        const size_t ta = ((size_t)(n * 8 + q128a) * 8 + jt) * 512;
        const size_t tb = ((size_t)(n * 8 + q128b) * 8 + jt) * 512;
        gload_lds4(bits + ta + t, &Mb[mb][wave * 16][0]);
        gload_lds4(bits + tb + t, &Mb[mb][128 + wave * 16][0]);
    };
    auto cls2 = [&](int jt, int& a, int& b) {
        if (cls) { a = cls[(n * 8 + q128a) * 8 + jt]; b = cls[(n * 8 + q128b) * 8 + jt]; }
        else     { a = 2; b = 2; }
    };

    int cur = 0;                       // tile 0 always non-empty (causal)
    stage(0, 0);
    if (hasb) stage_mask(0, 0);
    int buf = 0;

    while (cur < 8) {
        int cc0, cc1;
        cls2(cur, cc0, cc1);
        int nx = cur + 1;
        while (nx < 8) {
            int a, b; cls2(nx, a, b);
            if (a | b) break;
            ++nx;
        }

        __builtin_amdgcn_sched_barrier(0);
        __builtin_amdgcn_s_barrier();          // readers of buf^1 / Mb[buf^1] done
        __builtin_amdgcn_sched_barrier(0);

        if (nx < 8) {
            stage(nx, buf ^ 1);
            if (hasb) stage_mask(nx, buf ^ 1);
        }
        __builtin_amdgcn_sched_barrier(0);
        // retire tile cur's loads (issued one compute ago); keep nx in flight
        if (nx < 8) {
            if (hasb) { asm volatile("s_waitcnt vmcnt(6)" ::: "memory"); }
            else      { asm volatile("s_waitcnt vmcnt(4)" ::: "memory"); }
        } else {
            asm volatile("s_waitcnt vmcnt(0)" ::: "memory");
        }
        __builtin_amdgcn_sched_barrier(0);
        __builtin_amdgcn_s_barrier();          // tile cur visible to all waves
        __builtin_amdgcn_sched_barrier(0);

        const int ch = half ? cc1 : cc0;       // this wave's half's class
        if (ch != 0) {
            const u16* Kb = &Ks2[buf][0];
            const u16* Vb = &Vs2[buf][0];

            // ---- swapped QK^T, both q-subtiles sharing the K reads ----
            f32x4 S0[8], S1[8];
            __builtin_amdgcn_s_setprio(1);
#pragma unroll
            for (int sub = 0; sub < 8; ++sub) {
                const int row = sub * 16 + l16;
                short8 k0 = *(const short8*)&Kb[row * 64 + ((quad ^ x7) * 8)];
                short8 k1 = *(const short8*)&Kb[row * 64 + (((4 + quad) ^ x7) * 8)];
                S0[sub] = __builtin_amdgcn_mfma_f32_16x16x32_bf16(k0, qf[0][0], (f32x4)0.0f, 0, 0, 0);
                S1[sub] = __builtin_amdgcn_mfma_f32_16x16x32_bf16(k0, qf[1][0], (f32x4)0.0f, 0, 0, 0);
                S0[sub] = __builtin_amdgcn_mfma_f32_16x16x32_bf16(k1, qf[0][1], S0[sub], 0, 0, 0);
                S1[sub] = __builtin_amdgcn_mfma_f32_16x16x32_bf16(k1, qf[1][1], S1[sub], 0, 0, 0);
            }
            __builtin_amdgcn_s_setprio(0);

            if (ch == 1) {
                const int mrow0 = half * 128 + w4 * 16 + l16;
                const uint4 mwa = *(const uint4*)&Mb[buf][mrow0][0];
                const uint4 mwb = *(const uint4*)&Mb[buf][mrow0 + 64][0];
#pragma unroll
                for (int sub = 0; sub < 8; ++sub) {
                    const u32 sa = (sub >> 1) == 0 ? mwa.x : (sub >> 1) == 1 ? mwa.y
                                 : (sub >> 1) == 2 ? mwa.z : mwa.w;
                    const u32 sb = (sub >> 1) == 0 ? mwb.x : (sub >> 1) == 1 ? mwb.y
                                 : (sub >> 1) == 2 ? mwb.z : mwb.w;
#pragma unroll
                    for (int reg = 0; reg < 4; ++reg) {
                        const u32 bitp = (sub & 1) * 16 + quad * 4 + reg;
                        if (!((sa >> bitp) & 1u)) S0[sub][reg] = -1e30f;
                        if (!((sb >> bitp) & 1u)) S1[sub][reg] = -1e30f;
                    }
                }
            }

            // ---- lane-local softmax + packed b64 P-store (both s) ----
            float rs0 = 0.0f, rs1 = 0.0f;
#pragma unroll
            for (int sub = 0; sub < 8; ++sub) {
                float a0 = exp2f(S0[sub][0]);
                float a1 = exp2f(S0[sub][1]);
                float a2 = exp2f(S0[sub][2]);
                float a3 = exp2f(S0[sub][3]);
                rs0 += (a0 + a1) + (a2 + a3);
                ushort4 pk;
                pk.x = f2bf_trunc(a0); pk.y = f2bf_trunc(a1);
                pk.z = f2bf_trunc(a2); pk.w = f2bf_trunc(a3);
                *(ushort4*)&Ps[wave][l16 * PSTR + sub * 16 + quad * 4] = pk;
                float b0 = exp2f(S1[sub][0]);
                float b1 = exp2f(S1[sub][1]);
                float b2 = exp2f(S1[sub][2]);
                float b3 = exp2f(S1[sub][3]);
                rs1 += (b0 + b1) + (b2 + b3);
                ushort4 qk;
                qk.x = f2bf_trunc(b0); qk.y = f2bf_trunc(b1);
                qk.z = f2bf_trunc(b2); qk.w = f2bf_trunc(b3);
                *(ushort4*)&Ps[wave][(16 + l16) * PSTR + sub * 16 + quad * 4] = qk;
            }
            rs0 += __shfl_xor(rs0, 16);
            rs0 += __shfl_xor(rs0, 32);
            lq[0] += rs0;
            rs1 += __shfl_xor(rs1, 16);
            rs1 += __shfl_xor(rs1, 32);
            lq[1] += rs1;

            // ---- O += P V, both q-subtiles sharing the V reads ----
            short8 pa0[4], pa1[4];
#pragma unroll
            for (int ks = 0; ks < 4; ++ks) {
                pa0[ks] = *(const short8*)&Ps[wave][l16 * PSTR + ks * 32 + quad * 8];
                pa1[ks] = *(const short8*)&Ps[wave][(16 + l16) * PSTR + ks * 32 + quad * 8];
            }
            __builtin_amdgcn_s_setprio(1);
#pragma unroll
            for (int d = 0; d < 4; ++d) {
                const int row = d * 16 + l16;
#pragma unroll
                for (int ks = 0; ks < 4; ++ks) {
                    short8 vb = *(const short8*)&Vb[row * 128 + (((ks * 4 + quad) ^ l16) & 15) * 8];
                    O[0][d] = __builtin_amdgcn_mfma_f32_16x16x32_bf16(pa0[ks], vb, O[0][d], 0, 0, 0);
                    O[1][d] = __builtin_amdgcn_mfma_f32_16x16x32_bf16(pa1[ks], vb, O[1][d], 0, 0, 0);
                }
            }
            __builtin_amdgcn_s_setprio(0);
        }

        buf ^= 1;
        cur = nx;
    }

    // ---- redistribute per-query sums (lq lives at lane l16 = query) ----
    float dv[2][4];
#pragma unroll
    for (int s = 0; s < 2; ++s)
#pragma unroll
        for (int reg = 0; reg < 4; ++reg)
            dv[s][reg] = __shfl(lq[s], quad * 4 + reg);

    // ---- normalize + write into the consumed Q section ----
#pragma unroll
    for (int s = 0; s < 2; ++s) {
#pragma unroll
        for (int d = 0; d < 4; ++d) {
#pragma unroll
            for (int reg = 0; reg < 4; ++reg) {
                const int row = i0 + half * 128 + s * 64 + w4 * 16 + quad * 4 + reg;
                const int col = h * 64 + d * 16 + l16;
                Yout[((size_t)n * SEQ + row) * QS + col] = f2bf(O[s][d][reg] / dv[s][reg]);
            }
        }
    }
}

// ---------------------------------------------------------------------------
// Fused: LN( p0 + p1 + bias + resid ) -> fp32 out + optional bf16 out.
// ---------------------------------------------------------------------------
__global__ __launch_bounds__(256) void ln_fused2(const float* __restrict__ p0,
                                                 const float* __restrict__ p1,
                                                 const float* __restrict__ bias,
                                                 const float* __restrict__ resid,
                                                 const float* __restrict__ g,
                                                 const float* __restrict__ be,
                                                 float* __restrict__ Y,
                                                 u16* __restrict__ Yb) {
    const int row = blockIdx.x;
    const int t = threadIdx.x;
    __shared__ float red[256];

    const float4 a = ((const float4*)(p0 + (size_t)row * MD))[t];
    const float4 b = ((const float4*)(p1 + (size_t)row * MD))[t];
    const float4 r = ((const float4*)(resid + (size_t)row * MD))[t];
    const float4 bi = ((const float4*)bias)[t];
    float4 v;
    v.x = a.x + b.x + r.x + bi.x;
    v.y = a.y + b.y + r.y + bi.y;
    v.z = a.z + b.z + r.z + bi.z;
    v.w = a.w + b.w + r.w + bi.w;

    red[t] = v.x + v.y + v.z + v.w;
    __syncthreads();
    for (int s2 = 128; s2 > 0; s2 >>= 1) {
        if (t < s2) red[t] += red[t + s2];
        __syncthreads();
    }
    const float mu = red[0] * (1.0f / MD);
    __syncthreads();

    float dx = v.x - mu, dy = v.y - mu, dz = v.z - mu, dw = v.w - mu;
    red[t] = dx * dx + dy * dy + dz * dz + dw * dw;
    __syncthreads();
    for (int s2 = 128; s2 > 0; s2 >>= 1) {
        if (t < s2) red[t] += red[t + s2];
        __syncthreads();
    }
    const float var = red[0] * (1.0f / MD);
    const float rs = rsqrtf(var + EPSF);

    const float4 gv = ((const float4*)g)[t];
    const float4 bv = ((const float4*)be)[t];
    float4 o;
    o.x = dx * rs * gv.x + bv.x;
    o.y = dy * rs * gv.y + bv.y;
    o.z = dz * rs * gv.z + bv.z;
    o.w = dw * rs * gv.w + bv.w;
    if (Y) ((float4*)(Y + (size_t)row * MD))[t] = o;
    if (Yb) {
        ushort4 ob;
        ob.x = f2bf(o.x); ob.y = f2bf(o.y); ob.z = f2bf(o.z); ob.w = f2bf(o.w);
        ((ushort4*)(Yb + (size_t)row * MD))[t] = ob;
    }
}

// ---------------------------------------------------------------------------
// Workspace map (MB), liveness unchanged:
//   0-8    decb -> O2b -> Pcross(low) -> Hb
//   8-16   encb -> Pcross(high) -> Hb
//   16-32  weight repacks (dead after out-projs) -> Hb
//   32-40  W1T   40-48 W2T
//   48-72  QKVb -> O4b(48-56) -> FP1(48-64)
//   72-80  Vt
//   80-96  mcls/mbits (self-attn only) -> Tb = partial p0 (all split-K)
//   96-112 Pself == O2 == O4 (row-aligned aliasing, safe)
// ---------------------------------------------------------------------------
extern "C" void kernel_launch(void* const* d_in, const int* in_sizes, int n_in,
                              void* d_out, int out_size, void* d_ws, size_t ws_size,
                              hipStream_t stream) {
    const float* dec  = (const float*)d_in[0];
    const float* enc  = (const float*)d_in[1];
    const int*   mask = (const int*)d_in[2];
    const float* Wq_s = (const float*)d_in[3];
    const float* bq_s = (const float*)d_in[4];
    const float* Wk_s = (const float*)d_in[5];
    const float* bk_s = (const float*)d_in[6];
    const float* Wv_s = (const float*)d_in[7];
    const float* bv_s = (const float*)d_in[8];
    const float* Wo_s = (const float*)d_in[9];
    const float* bo_s = (const float*)d_in[10];
    const float* Wq_c = (const float*)d_in[11];
    const float* bq_c = (const float*)d_in[12];
    const float* Wk_c = (const float*)d_in[13];
    const float* bk_c = (const float*)d_in[14];
    const float* Wv_c = (const float*)d_in[15];
    const float* bv_c = (const float*)d_in[16];
    const float* Wo_c = (const float*)d_in[17];
    const float* bo_c = (const float*)d_in[18];
    const float* W1   = (const float*)d_in[19];
    const float* b1   = (const float*)d_in[20];
    const float* W2   = (const float*)d_in[21];
    const float* b2   = (const float*)d_in[22];
    const float* g1   = (const float*)d_in[23];
    const float* be1  = (const float*)d_in[24];
    const float* g2   = (const float*)d_in[25];
    const float* be2  = (const float*)d_in[26];
    const float* g3   = (const float*)d_in[27];
    const float* be3  = (const float*)d_in[28];

    char* wsb = (char*)d_ws;
    const size_t MB = 1u << 20;
    u16*   decb  = (u16*)(wsb + 0 * MB);
    u16*   O2b   = (u16*)(wsb + 0 * MB);
    u16*   encb  = (u16*)(wsb + 8 * MB);
    u16*   WqkvsT= (u16*)(wsb + 16 * MB);
    u16*   WqkvcT= (u16*)(wsb + 22 * MB);
    u16*   WosT  = (u16*)(wsb + 28 * MB);
    u16*   WocT  = (u16*)(wsb + 30 * MB);
    u16*   W1T   = (u16*)(wsb + 32 * MB);
    u16*   W2T   = (u16*)(wsb + 40 * MB);
    u16*   QKVb  = (u16*)(wsb + 48 * MB);
    u16*   O4b   = (u16*)(wsb + 48 * MB);
    u16*   Vt    = (u16*)(wsb + 72 * MB);
    u16*   Hb    = (u16*)(wsb + 0 * MB);
    int*   mcls  = (int*)(wsb + 80 * MB);
    u32*   mbits = (u32*)(wsb + 80 * MB + 64 * 1024);
    float* Tb    = (float*)(wsb + 80 * MB);
    float* Pself = (float*)(wsb + 96 * MB);
    float* Pcross= (float*)(wsb + 0 * MB);
    float* O2    = (float*)(wsb + 96 * MB);
    float* O4    = (float*)(wsb + 96 * MB);
    float* FP1   = (float*)(wsb + 48 * MB);

    dim3 blk(256);
    dim3 blk5(512);
    dim3 gConv(NK * MD / 4 / 256, 2);
    dim3 gMask(8, 8, 4);
    dim3 gQkvW(16, 16, 6);
    dim3 gFlatW(16, 16, 10);
    dim3 gAttn(SEQ / 256, NH, NB);
    dim3 gQKV(QS / 256, NK / 256);
    dim3 gOut(MD / 128, NK / 256, 2);
    dim3 gF1(FF / 256, NK / 256);
    dim3 gF2(MD / 128, NK / 256, 2);

    // ---- converts + repacks + mask precompute ----
    conv_bf16<<<gConv, blk, 0, stream>>>(dec, enc, decb, encb);
    mask_tiles<<<gMask, blk, 0, stream>>>(mask, mcls, mbits);

    QkvArgs qa;
    qa.src[0] = Wq_s; qa.src[1] = Wk_s; qa.src[2] = Wv_s;
    qa.src[3] = Wq_c; qa.src[4] = Wk_c; qa.src[5] = Wv_c;
    qa.dst[0] = WqkvsT;                 qa.dst[1] = WqkvsT + (size_t)1024 * 1024;
    qa.dst[2] = WqkvsT + (size_t)2048 * 1024;
    qa.dst[3] = WqkvcT;                 qa.dst[4] = WqkvcT + (size_t)1024 * 1024;
    qa.dst[5] = WqkvcT + (size_t)2048 * 1024;
    repack_qkv<<<gQkvW, blk, 0, stream>>>(qa);

    FlatArgs fa;
    fa.d[0] = { Wo_s, 1024, WosT, 1024 };
    fa.d[1] = { Wo_c, 1024, WocT, 1024 };
    for (int u = 0; u < 4; ++u)
        fa.d[2 + u] = { W1 + (size_t)u * 1024, 4096, W1T + (size_t)u * 1024 * 1024, 1024 };
    for (int u = 0; u < 4; ++u)
        fa.d[6 + u] = { W2 + (size_t)u * 1024 * 1024, 1024, W2T + (size_t)u * 1024, 4096 };
    repack_flat<<<gFlatW, blk, 0, stream>>>(fa);

    // ---- self attention ----
    gemm_256<0, 1, 1, 0><<<gQKV, blk5, 0, stream>>>(decb, decb, MD, WqkvsT, MD, bq_s, bk_s, bv_s, QKVb, Vt, MD, QS);
    attn_mfma<<<gAttn, blk5, 0, stream>>>(QKVb, Vt, mcls, mbits, QKVb);
    gemm_sk<<<gOut, blk5, 0, stream>>>(QKVb, QS, WosT, MD, Tb, Pself, MD / 2, MD);
    ln_fused2<<<NK, blk, 0, stream>>>(Tb, Pself, bo_s, dec, g1, be1, O2, O2b);

    // ---- cross attention ----
    gemm_256<0, 1, 1, 0><<<gQKV, blk5, 0, stream>>>(O2b, encb, MD, WqkvcT, MD, bq_c, bk_c, bv_c, QKVb, Vt, MD, QS);
    attn_mfma<<<gAttn, blk5, 0, stream>>>(QKVb, Vt, nullptr, nullptr, QKVb);
    gemm_sk<<<gOut, blk5, 0, stream>>>(QKVb, QS, WocT, MD, Tb, Pcross, MD / 2, MD);
    ln_fused2<<<NK, blk, 0, stream>>>(Tb, Pcross, bo_c, O2, g2, be2, O4, O4b);

    // ---- feed-forward (FFN1 on 256-tile C^T; FFN2 split-K=2 fused into LN) ----
    gemm_256<1, 0, 0, 1><<<gF1, blk5, 0, stream>>>(O4b, O4b, MD, W1T, MD, b1, nullptr, nullptr, Hb, nullptr, MD, FF);
    gemm_sk<<<gF2, blk5, 0, stream>>>(Hb, FF, W2T, FF, Tb, FP1, FF / 2, MD);
    ln_fused2<<<NK, blk, 0, stream>>>(Tb, FP1, b2, O4, g3, be3, (float*)d_out, nullptr);
}

// Round 16
// 480.046 us; speedup vs baseline: 1.0145x; 1.0145x over previous
//
#include <hip/hip_runtime.h>

#define NB   4
#define SEQ  1024
#define MD   1024
#define NH   16
#define HD   64
#define FF   4096
#define NK   (NB*SEQ)
#define EPSF 1e-5f
#define QS   3072          // fused QKV row stride (bf16 elems)

typedef short short8 __attribute__((ext_vector_type(8)));
typedef float f32x4  __attribute__((ext_vector_type(4)));
typedef unsigned short u16;
typedef unsigned int u32;

__device__ __forceinline__ u16 f2bf(float x) {
    union { float f; unsigned u; } v; v.f = x;
    unsigned r = v.u + 0x7FFF + ((v.u >> 16) & 1);
    return (u16)(r >> 16);
}
__device__ __forceinline__ u16 f2bf_trunc(float x) {   // positive values
    union { float f; unsigned u; } v; v.f = x;
    return (u16)(v.u >> 16);
}
__device__ __forceinline__ float bf2f(u16 x) {
    union { unsigned u; float f; } v; v.u = ((unsigned)x) << 16;
    return v.f;
}
__device__ __forceinline__ void gload_lds16(const void* g, void* l) {
    __builtin_amdgcn_global_load_lds(
        (const __attribute__((address_space(1))) unsigned int*)g,
        (__attribute__((address_space(3))) unsigned int*)l,
        16, 0, 0);
}
__device__ __forceinline__ void gload_lds4(const void* g, void* l) {
    __builtin_amdgcn_global_load_lds(
        (const __attribute__((address_space(1))) unsigned int*)g,
        (__attribute__((address_space(3))) unsigned int*)l,
        4, 0, 0);
}

// ---------------------------------------------------------------------------
// dec+enc fp32 -> bf16. Grid (4096, 2).
// ---------------------------------------------------------------------------
__global__ __launch_bounds__(256) void conv_bf16(const float* __restrict__ s0,
                                                 const float* __restrict__ s1,
                                                 u16* __restrict__ d0,
                                                 u16* __restrict__ d1) {
    const float* S = blockIdx.y ? s1 : s0;
    u16* D = blockIdx.y ? d1 : d0;
    const int i = blockIdx.x * 256 + threadIdx.x;
    float4 v = ((const float4*)S)[i];
    ushort4 o;
    o.x = f2bf(v.x); o.y = f2bf(v.y); o.z = f2bf(v.z); o.w = f2bf(v.w);
    ((ushort4*)D)[i] = o;
}

// ---------------------------------------------------------------------------
// Mask tile precompute for 128x128 tiles. Grid (8,8,4), blk 256.
// ---------------------------------------------------------------------------
__global__ __launch_bounds__(256) void mask_tiles(const int* __restrict__ mask,
                                                  int* __restrict__ cls,
                                                  u32* __restrict__ bits) {
    const int jt = blockIdx.x, qt = blockIdx.y, n = blockIdx.z;
    const int t = threadIdx.x;
    const int r = t >> 1, h2 = (t & 1) * 2;
    u32 bb[2];
#pragma unroll
    for (int sg = 0; sg < 2; ++sg) {
        const int* mp = &mask[((size_t)n * SEQ + qt * 128 + r) * SEQ + jt * 128 + (h2 + sg) * 32];
        u32 b = 0;
#pragma unroll
        for (int k = 0; k < 8; ++k) {
            int4 v = *(const int4*)(mp + k * 4);
            b |= (v.x ? 1u : 0u) << (k * 4 + 0);
            b |= (v.y ? 1u : 0u) << (k * 4 + 1);
            b |= (v.z ? 1u : 0u) << (k * 4 + 2);
            b |= (v.w ? 1u : 0u) << (k * 4 + 3);
        }
        bb[sg] = b;
    }
    const int tile = (n * 8 + qt) * 8 + jt;
    bits[((size_t)tile * 128 + r) * 4 + h2]     = bb[0];
    bits[((size_t)tile * 128 + r) * 4 + h2 + 1] = bb[1];
    const int nfull  = __syncthreads_count(bb[0] == 0xFFFFFFFFu && bb[1] == 0xFFFFFFFFu);
    const int nempty = __syncthreads_count(bb[0] == 0u && bb[1] == 0u);
    if (t == 0) cls[tile] = (nfull == 256) ? 2 : ((nempty == 256) ? 0 : 1);
}

// ---------------------------------------------------------------------------
// QKV weight repack (6 heads-major weights -> fused transposed buffers).
// ---------------------------------------------------------------------------
struct QkvArgs { const float* src[6]; u16* dst[6]; };

__global__ __launch_bounds__(256) void repack_qkv(QkvArgs a) {
    const int m0 = blockIdx.x * 64;
    const int h  = blockIdx.y;
    const int w  = blockIdx.z;
    const float* W = a.src[w];
    u16* BT = a.dst[w];
    const int t = threadIdx.x;
    __shared__ u16 Ts[64][72];

    const int r = t >> 4, c4 = (t & 15) * 4;
#pragma unroll
    for (int p = 0; p < 4; ++p) {
        const int row = r + p * 16;
        float4 v = *(const float4*)&W[((size_t)h * 1024 + m0 + row) * 64 + c4];
        Ts[row][c4] = f2bf(v.x); Ts[row][c4 + 1] = f2bf(v.y);
        Ts[row][c4 + 2] = f2bf(v.z); Ts[row][c4 + 3] = f2bf(v.w);
    }
    __syncthreads();
    const int d = t >> 2, j0 = (t & 3) * 16;
#pragma unroll
    for (int p = 0; p < 4; ++p) {
        ushort4 o;
        o.x = Ts[j0 + p * 4 + 0][d]; o.y = Ts[j0 + p * 4 + 1][d];
        o.z = Ts[j0 + p * 4 + 2][d]; o.w = Ts[j0 + p * 4 + 3][d];
        *(ushort4*)&BT[((size_t)h * 64 + d) * 1024 + m0 + j0 + p * 4] = o;
    }
}

// ---------------------------------------------------------------------------
// Flat weight repacks via descriptors. Grid (16,16,10).
// ---------------------------------------------------------------------------
struct FD { const float* src; int ss; u16* dst; int ds; };
struct FlatArgs { FD d[10]; };

__global__ __launch_bounds__(256) void repack_flat(FlatArgs fa) {
    FD u = fa.d[blockIdx.z];
    const int r0 = blockIdx.x * 64;
    const int c0 = blockIdx.y * 64;
    const int t  = threadIdx.x;
    __shared__ u16 Ts[64][72];

    const int r = t >> 4, c4 = (t & 15) * 4;
#pragma unroll
    for (int p = 0; p < 4; ++p) {
        const int row = r + p * 16;
        float4 v = *(const float4*)&u.src[(size_t)(r0 + row) * u.ss + c0 + c4];
        Ts[row][c4] = f2bf(v.x); Ts[row][c4 + 1] = f2bf(v.y);
        Ts[row][c4 + 2] = f2bf(v.z); Ts[row][c4 + 3] = f2bf(v.w);
    }
    __syncthreads();
    const int d = t >> 2, j0 = (t & 3) * 16;
#pragma unroll
    for (int p = 0; p < 4; ++p) {
        ushort4 o;
        o.x = Ts[j0 + p * 4 + 0][d]; o.y = Ts[j0 + p * 4 + 1][d];
        o.z = Ts[j0 + p * 4 + 2][d]; o.w = Ts[j0 + p * 4 + 3][d];
        *(ushort4*)&u.dst[(size_t)(c0 + d) * u.ds + r0 + j0 + p * 4] = o;
    }
}

// ---------------------------------------------------------------------------
// gemm_256: 256x256 block tile, 8 waves (2M x 4N), per-wave 128x64 output.
// K-slice ring pipeline, counted vmcnt(8). VT epilogue via LDS transpose
// (R11: kills 8x write amplification). CT (R13): C^T shfl-packed 64 B-run
// stores (used by FFN1). R14: interior sched_barrier fences removed.
// ---------------------------------------------------------------------------
template<int RELU, int BIAS3, int VT, int CT>
__global__ __launch_bounds__(512, 2) void gemm_256(const u16* __restrict__ A,
                                                   const u16* __restrict__ A2,
                                                   int Astride,
                                                   const u16* __restrict__ BT,
                                                   int Bstride,
                                                   const float* __restrict__ b0,
                                                   const float* __restrict__ b1p,
                                                   const float* __restrict__ b2p,
                                                   u16* __restrict__ Cout,
                                                   u16* __restrict__ VtOut,
                                                   int Kd, int Nd) {
    const u32 gx = gridDim.x, gy = gridDim.y;
    const u32 T  = gx * gy;
    const u32 dd = blockIdx.y * gx + blockIdx.x;
    const u32 wid = (dd & 7) * (T >> 3) + (dd >> 3);
    const int nt = wid % gx;
    const int mt = wid / gx;

    const int t  = threadIdx.x;
    const int wave = t >> 6, lane = t & 63;
    const int q = lane >> 4, l16 = lane & 15;
    const int wm = wave >> 2, wn = wave & 3;       // 2M x 4N
    const int srow = lane >> 2, schk = lane & 3;

    __shared__ __align__(16) u16 As[4][256 * 32];  // 64 KB
    __shared__ __align__(16) u16 Bs[4][256 * 32];  // 64 KB

    const int row0 = mt * 256, col0 = nt * 256;
    const u16* Ause = (col0 < 1024) ? A : A2;
    const int ns = Kd / 32;

    f32x4 acc[8][4];
#pragma unroll
    for (int r = 0; r < 8; ++r)
#pragma unroll
        for (int c = 0; c < 4; ++c) acc[r][c] = (f32x4)0.0f;

    auto stage = [&](int ss) {
        const int k0 = ss * 32;
        u16* Ad = &As[ss & 3][0];
        u16* Bd = &Bs[ss & 3][0];
#pragma unroll
        for (int p = 0; p < 2; ++p) {
            const int rg = wave * 32 + p * 16 + srow;
            const int gc = schk ^ ((rg >> 1) & 3);
            gload_lds16(Ause + (size_t)(row0 + rg) * Astride + k0 + gc * 8,
                        Ad + (wave * 32 + p * 16) * 32);
            gload_lds16(BT + (size_t)(col0 + rg) * Bstride + k0 + gc * 8,
                        Bd + (wave * 32 + p * 16) * 32);
        }
    };

    stage(0);
    if (ns > 1) stage(1);
    if (ns > 2) stage(2);

    for (int s = 0; s < ns; ++s) {
        const int lead = ns - 1 - s;
        if (lead >= 2)      { asm volatile("s_waitcnt vmcnt(8)" ::: "memory"); }
        else if (lead == 1) { asm volatile("s_waitcnt vmcnt(4)" ::: "memory"); }
        else                { asm volatile("s_waitcnt vmcnt(0)" ::: "memory"); }
        __builtin_amdgcn_sched_barrier(0);
        __builtin_amdgcn_s_barrier();
        __builtin_amdgcn_sched_barrier(0);

        const u16* Ab = &As[s & 3][0];
        const u16* Bb = &Bs[s & 3][0];
        short8 af[8], bf[4];
#pragma unroll
        for (int fr = 0; fr < 8; ++fr) {
            const int ar = wm * 128 + fr * 16 + l16;
            af[fr] = *(const short8*)&Ab[ar * 32 + ((q ^ ((ar >> 1) & 3)) * 8)];
        }
#pragma unroll
        for (int fc = 0; fc < 4; ++fc) {
            const int br = wn * 64 + fc * 16 + l16;
            bf[fc] = *(const short8*)&Bb[br * 32 + ((q ^ ((br >> 1) & 3)) * 8)];
        }

        if (s + 3 < ns) stage(s + 3);

        __builtin_amdgcn_s_setprio(1);
#pragma unroll
        for (int fr = 0; fr < 8; ++fr)
#pragma unroll
            for (int fc = 0; fc < 4; ++fc) {
                if (CT)
                    acc[fr][fc] = __builtin_amdgcn_mfma_f32_16x16x32_bf16(bf[fc], af[fr], acc[fr][fc], 0, 0, 0);
                else
                    acc[fr][fc] = __builtin_amdgcn_mfma_f32_16x16x32_bf16(af[fr], bf[fc], acc[fr][fc], 0, 0, 0);
            }
        __builtin_amdgcn_s_setprio(0);
        __builtin_amdgcn_sched_barrier(0);
    }

    if (VT && !CT && col0 >= 2048) {
        // ---- coalesced Vt epilogue via LDS transpose ----
        __builtin_amdgcn_s_barrier();          // all waves done reading As/Bs
        u16* LT = (wn < 2) ? (&As[0][0] + wn * 16384) : (&Bs[0][0] + (wn - 2) * 16384);
#pragma unroll
        for (int fc = 0; fc < 4; ++fc) {
            const int d = fc * 16 + l16;
            const float bb = b2p[(col0 + wn * 64 + d) & 1023];
#pragma unroll
            for (int fr = 0; fr < 8; ++fr) {
                const int kb  = wm * 32 + fr * 4 + q;   // 8B k-chunk index
                const int kbs = kb ^ l16;               // bank spread (bijective per d)
                ushort4 o;
                o.x = f2bf(acc[fr][fc][0] + bb);
                o.y = f2bf(acc[fr][fc][1] + bb);
                o.z = f2bf(acc[fr][fc][2] + bb);
                o.w = f2bf(acc[fr][fc][3] + bb);
                *(ushort4*)&LT[d * 256 + kbs * 4] = o;
            }
        }
        __builtin_amdgcn_s_barrier();
        const int nn = row0 >> 10, k0 = row0 & 1023;
        const int hbase = (col0 - 2048) >> 6;
#pragma unroll
        for (int it = 0; it < 16; ++it) {
            const int c  = it * 512 + t;
            const int hh = c >> 11;
            const int r  = c & 2047;
            const int d  = r >> 5;
            const int kc = r & 31;                 // 8-elem k chunk
            const u16* LR = (hh < 2) ? (&As[0][0] + hh * 16384) : (&Bs[0][0] + (hh - 2) * 16384);
            const int x   = d & 15;
            const int kb0 = (kc * 2) ^ x;
            const int kb1 = kb0 ^ 1;
            uint2 lo = *(const uint2*)&LR[d * 256 + kb0 * 4];
            uint2 hi = *(const uint2*)&LR[d * 256 + kb1 * 4];
            uint4 o4; o4.x = lo.x; o4.y = lo.y; o4.z = hi.x; o4.w = hi.y;
            *(uint4*)&VtOut[((size_t)(nn * 16 + hbase + hh) * 64 + d) * 1024 + k0 + kc * 8] = o4;
        }
        return;
    }

    if (CT) {
        // ---- C^T epilogue: shfl-pack to 64 B-per-row uint4 stores ----
#pragma unroll
        for (int p2 = 0; p2 < 2; ++p2) {
            const int fcA = p2 * 2, fcB = p2 * 2 + 1;
            const int colbase = col0 + wn * 64 + fcA * 16;
            float4 bbA, bbB;
            if (BIAS3) {
                bbA = *(const float4*)&b0[(colbase + q * 4) & 1023];
                bbB = *(const float4*)&b0[(colbase + 16 + q * 4) & 1023];
            } else {
                bbA = *(const float4*)&b0[colbase + q * 4];
                bbB = *(const float4*)&b0[colbase + 16 + q * 4];
            }
#pragma unroll
            for (int fr = 0; fr < 8; ++fr) {
                float a0 = acc[fr][fcA][0] + bbA.x;
                float a1 = acc[fr][fcA][1] + bbA.y;
                float a2 = acc[fr][fcA][2] + bbA.z;
                float a3 = acc[fr][fcA][3] + bbA.w;
                float b0v = acc[fr][fcB][0] + bbB.x;
                float b1v = acc[fr][fcB][1] + bbB.y;
                float b2v = acc[fr][fcB][2] + bbB.z;
                float b3v = acc[fr][fcB][3] + bbB.w;
                if (RELU) {
                    a0 = fmaxf(a0, 0.0f); a1 = fmaxf(a1, 0.0f);
                    a2 = fmaxf(a2, 0.0f); a3 = fmaxf(a3, 0.0f);
                    b0v = fmaxf(b0v, 0.0f); b1v = fmaxf(b1v, 0.0f);
                    b2v = fmaxf(b2v, 0.0f); b3v = fmaxf(b3v, 0.0f);
                }
                u32 u0lo = (u32)f2bf(a0) | ((u32)f2bf(a1) << 16);
                u32 u0hi = (u32)f2bf(a2) | ((u32)f2bf(a3) << 16);
                u32 u1lo = (u32)f2bf(b0v) | ((u32)f2bf(b1v) << 16);
                u32 u1hi = (u32)f2bf(b2v) | ((u32)f2bf(b3v) << 16);
                u32 x0lo = (u32)__shfl_xor((int)u0lo, 16);
                u32 x0hi = (u32)__shfl_xor((int)u0hi, 16);
                u32 x1lo = (u32)__shfl_xor((int)u1lo, 16);
                u32 x1hi = (u32)__shfl_xor((int)u1hi, 16);
                uint4 o;
                if (q & 1) { o.x = x1lo; o.y = x1hi; o.z = u1lo; o.w = u1hi; }
                else       { o.x = u0lo; o.y = u0hi; o.z = x0lo; o.w = x0hi; }
                const int coloff = (q & 1) * 16 + (q & 2) * 4;
                const int row = row0 + wm * 128 + fr * 16 + l16;
                *(uint4*)&Cout[(size_t)row * Nd + colbase + coloff] = o;
            }
        }
        return;
    }

#pragma unroll
    for (int fc = 0; fc < 4; ++fc) {
        const int col = col0 + wn * 64 + fc * 16 + l16;
        float bb;
        if (BIAS3) {
            const int sec = col >> 10;
            const float* bp = sec == 0 ? b0 : (sec == 1 ? b1p : b2p);
            bb = bp[col & 1023];
        } else {
            bb = b0[col];
        }
#pragma unroll
        for (int fr = 0; fr < 8; ++fr) {
#pragma unroll
            for (int reg = 0; reg < 4; ++reg) {
                const int row = row0 + wm * 128 + fr * 16 + q * 4 + reg;
                float v = acc[fr][fc][reg] + bb;
                if (RELU) v = fmaxf(v, 0.0f);
                Cout[(size_t)row * Nd + col] = f2bf(v);
            }
        }
    }
}

// ---------------------------------------------------------------------------
// gemm_sk: split-K deep-pipeline GEMM for the N=1024 sites (proven R7/R14).
// 256x128 tile, 8 waves (4M x 2N), 96 KB 4-slot LDS ring, counted vmcnt(6).
// (R15's 3-slot variant reverted: grid = 256 blocks = 1/CU regardless of
// LDS, so shrinking the ring bought nothing and cost pipeline depth.)
// ---------------------------------------------------------------------------
__global__ __launch_bounds__(512, 2) void gemm_sk(const u16* __restrict__ A,
                                                  int Astride,
                                                  const u16* __restrict__ BT,
                                                  int Bstride,
                                                  float* __restrict__ P0,
                                                  float* __restrict__ P1,
                                                  int Kd, int Nd) {
    const u32 gx = gridDim.x, gy = gridDim.y;
    const u32 T  = gx * gy * gridDim.z;
    const u32 dd = (blockIdx.z * gy + blockIdx.y) * gx + blockIdx.x;
    const u32 wid = (dd & 7) * (T >> 3) + (dd >> 3);
    const int nt = wid % gx;
    const int mt = (wid / gx) % gy;
    const int zz = wid / (gx * gy);

    const int t  = threadIdx.x;
    const int wave = t >> 6, lane = t & 63;
    const int q = lane >> 4, l16 = lane & 15;
    const int wm = wave >> 1, wn = wave & 1;       // 4M x 2N
    const int srow = lane >> 2, schk = lane & 3;

    __shared__ __align__(16) u16 As[4][256 * 32];  // 64 KB
    __shared__ __align__(16) u16 Bs[4][128 * 32];  // 32 KB

    const int row0 = mt * 256, col0 = nt * 128;
    const int kBase = zz * Kd;
    const int ns = Kd / 32;

    f32x4 acc[4][4];
#pragma unroll
    for (int r = 0; r < 4; ++r)
#pragma unroll
        for (int c = 0; c < 4; ++c) acc[r][c] = (f32x4)0.0f;

    auto stage = [&](int ss) {
        const int k0 = kBase + ss * 32;
        u16* Ad = &As[ss & 3][0];
        u16* Bd = &Bs[ss & 3][0];
#pragma unroll
        for (int p = 0; p < 2; ++p) {
            const int rg = wave * 32 + p * 16 + srow;
            const int gc = schk ^ ((rg >> 1) & 3);
            gload_lds16(A + (size_t)(row0 + rg) * Astride + k0 + gc * 8,
                        Ad + (wave * 32 + p * 16) * 32);
        }
        {
            const int rb = wave * 16 + srow;
            const int gc = schk ^ ((rb >> 1) & 3);
            gload_lds16(BT + (size_t)(col0 + rb) * Bstride + k0 + gc * 8,
                        Bd + (wave * 16) * 32);
        }
    };

    stage(0);
    if (ns > 1) stage(1);
    if (ns > 2) stage(2);

    const int pb = (q ^ ((l16 >> 1) & 3)) * 8;

    for (int s = 0; s < ns; ++s) {
        const int lead = ns - 1 - s;
        if (lead >= 2)      { asm volatile("s_waitcnt vmcnt(6)" ::: "memory"); }
        else if (lead == 1) { asm volatile("s_waitcnt vmcnt(3)" ::: "memory"); }
        else                { asm volatile("s_waitcnt vmcnt(0)" ::: "memory"); }
        __builtin_amdgcn_sched_barrier(0);
        __builtin_amdgcn_s_barrier();
        __builtin_amdgcn_sched_barrier(0);

        const u16* Ab = &As[s & 3][0];
        const u16* Bb = &Bs[s & 3][0];
        short8 af[4], bf[4];
#pragma unroll
        for (int r = 0; r < 4; ++r)
            af[r] = *(const short8*)&Ab[(wm * 64 + r * 16 + l16) * 32 + pb];
#pragma unroll
        for (int c = 0; c < 4; ++c)
            bf[c] = *(const short8*)&Bb[(wn * 64 + c * 16 + l16) * 32 + pb];

        if (s + 3 < ns) stage(s + 3);

        __builtin_amdgcn_s_setprio(1);
#pragma unroll
        for (int r = 0; r < 4; ++r)
#pragma unroll
            for (int c = 0; c < 4; ++c)
                acc[r][c] = __builtin_amdgcn_mfma_f32_16x16x32_bf16(af[r], bf[c], acc[r][c], 0, 0, 0);
        __builtin_amdgcn_s_setprio(0);
        __builtin_amdgcn_sched_barrier(0);
    }

    float* Pout = zz ? P1 : P0;
#pragma unroll
    for (int c = 0; c < 4; ++c) {
        const int col = col0 + wn * 64 + c * 16 + l16;
#pragma unroll
        for (int r = 0; r < 4; ++r) {
#pragma unroll
            for (int reg = 0; reg < 4; ++reg) {
                const int row = row0 + wm * 64 + r * 16 + q * 4 + reg;
                Pout[(size_t)row * Nd + col] = acc[r][c][reg];
            }
        }
    }
}

// ---------------------------------------------------------------------------
// MFMA flash attention v9 (R12-proven): v8 + shared LDS reads across the two
// q-subtiles.
// ---------------------------------------------------------------------------
#define PSTR 140

__global__ __launch_bounds__(512, 2) void attn_mfma(const u16* __restrict__ QKV,
                                                    const u16* __restrict__ Vt,
                                                    const int* __restrict__ cls,
                                                    const u32* __restrict__ bits,
                                                    u16* __restrict__ Yout) {
    const u32 T  = gridDim.x * gridDim.y * gridDim.z;   // 256
    const u32 dd = (blockIdx.z * gridDim.y + blockIdx.y) * gridDim.x + blockIdx.x;
    const u32 wid = (dd & 7) * (T >> 3) + (dd >> 3);
    const int qt = wid % gridDim.x;                      // 256-q tile
    const int h  = (wid / gridDim.x) % gridDim.y;
    const int n  = wid / (gridDim.x * gridDim.y);

    const int t    = threadIdx.x;
    const int wave = t >> 6;
    const int lane = t & 63;
    const int quad = lane >> 4;
    const int l16  = lane & 15;
    const int half = wave >> 2;        // 0: q-rows 0-127, 1: 128-255
    const int w4   = wave & 3;

    __shared__ __align__(16) u16 Ks2[2][128 * 64];   // 32 KB
    __shared__ __align__(16) u16 Vs2[2][64 * 128];   // 32 KB
    __shared__ __align__(16) u16 Ps[8][32 * PSTR];   // 70 KB (wave-private, both s)
    __shared__ u32 Mb[2][256][4];                    // 8 KB

    const int bh = n * NH + h;
    const int i0 = qt * 256;
    const int q128a = qt * 2, q128b = qt * 2 + 1;

    // Q fragments (2 q-subtiles of 16 rows per wave), pre-scaled by
    // 0.125*log2e. Used as the B operand of the swapped QK^T.
    short8 qf[2][2];
#pragma unroll
    for (int s = 0; s < 2; ++s) {
        const u16* qrow = QKV + ((size_t)n * SEQ + i0 + half * 128 + s * 64 + w4 * 16 + l16) * QS + h * 64 + quad * 8;
        short8 a = *(const short8*)(qrow);
        short8 b = *(const short8*)(qrow + 32);
#pragma unroll
        for (int j = 0; j < 8; ++j) {
            qf[s][0][j] = (short)f2bf(bf2f((u16)a[j]) * 0.18033688f);
            qf[s][1][j] = (short)f2bf(bf2f((u16)b[j]) * 0.18033688f);
        }
    }

    f32x4 O[2][4];
#pragma unroll
    for (int s = 0; s < 2; ++s)
#pragma unroll
        for (int d = 0; d < 4; ++d) O[s][d] = (f32x4)0.0f;
    float lq[2] = {0.0f, 0.0f};        // per-lane query (l16) running sum

    const int krow = lane >> 3, kblk = lane & 7;
    const int vrow = lane >> 4, vblk = lane & 15;
    const int x7 = l16 & 7;
    const int hasb = bits != nullptr;

    auto stage = [&](int jt, int b) {
#pragma unroll
        for (int p = 0; p < 2; ++p) {
            const int rr = wave * 16 + p * 8 + krow;
            const int kb = kblk ^ (rr & 7);
            gload_lds16(QKV + ((size_t)n * SEQ + jt * 128 + rr) * QS + 1024 + h * 64 + kb * 8,
                        &Ks2[b][(wave * 16 + p * 8) * 64]);
        }
#pragma unroll
        for (int p = 0; p < 2; ++p) {
            const int rr = wave * 8 + p * 4 + vrow;
            const int kb = vblk ^ (rr & 15);
            gload_lds16(Vt + ((size_t)bh * HD + rr) * SEQ + jt * 128 + kb * 8,
                        &Vs2[b][(wave * 8 + p * 4) * 128]);
        }
    };
    auto stage_mask = [&](int jt, int mb) {
        const size_t ta = ((size_t)(n * 8 + q128a) * 8 + jt) * 512;
        const size_t tb = ((size_t)(n * 8 + q128b) * 8 + jt) * 512;
        gload_lds4(bits + ta + t, &Mb[mb][wave * 16][0]);
        gload_lds4(bits + tb + t, &Mb[mb][128 + wave * 16][0]);
    };
    auto cls2 = [&](int jt, int& a, int& b) {
        if (cls) { a = cls[(n * 8 + q128a) * 8 + jt]; b = cls[(n * 8 + q128b) * 8 + jt]; }
        else     { a = 2; b = 2; }
    };

    int cur = 0;                       // tile 0 always non-empty (causal)
    stage(0, 0);
    if (hasb) stage_mask(0, 0);
    int buf = 0;

    while (cur < 8) {
        int cc0, cc1;
        cls2(cur, cc0, cc1);
        int nx = cur + 1;
        while (nx < 8) {
            int a, b; cls2(nx, a, b);
            if (a | b) break;
            ++nx;
        }

        __builtin_amdgcn_sched_barrier(0);
        __builtin_amdgcn_s_barrier();          // readers of buf^1 / Mb[buf^1] done
        __builtin_amdgcn_sched_barrier(0);

        if (nx < 8) {
            stage(nx, buf ^ 1);
            if (hasb) stage_mask(nx, buf ^ 1);
        }
        __builtin_amdgcn_sched_barrier(0);
        // retire tile cur's loads (issued one compute ago); keep nx in flight
        if (nx < 8) {
            if (hasb) { asm volatile("s_waitcnt vmcnt(6)" ::: "memory"); }
            else      { asm volatile("s_waitcnt vmcnt(4)" ::: "memory"); }
        } else {
            asm volatile("s_waitcnt vmcnt(0)" ::: "memory");
        }
        __builtin_amdgcn_sched_barrier(0);
        __builtin_amdgcn_s_barrier();          // tile cur visible to all waves
        __builtin_amdgcn_sched_barrier(0);

        const int ch = half ? cc1 : cc0;       // this wave's half's class
        if (ch != 0) {
            const u16* Kb = &Ks2[buf][0];
            const u16* Vb = &Vs2[buf][0];

            // ---- swapped QK^T, both q-subtiles sharing the K reads ----
            f32x4 S0[8], S1[8];
            __builtin_amdgcn_s_setprio(1);
#pragma unroll
            for (int sub = 0; sub < 8; ++sub) {
                const int row = sub * 16 + l16;
                short8 k0 = *(const short8*)&Kb[row * 64 + ((quad ^ x7) * 8)];
                short8 k1 = *(const short8*)&Kb[row * 64 + (((4 + quad) ^ x7) * 8)];
                S0[sub] = __builtin_amdgcn_mfma_f32_16x16x32_bf16(k0, qf[0][0], (f32x4)0.0f, 0, 0, 0);
                S1[sub] = __builtin_amdgcn_mfma_f32_16x16x32_bf16(k0, qf[1][0], (f32x4)0.0f, 0, 0, 0);
                S0[sub] = __builtin_amdgcn_mfma_f32_16x16x32_bf16(k1, qf[0][1], S0[sub], 0, 0, 0);
                S1[sub] = __builtin_amdgcn_mfma_f32_16x16x32_bf16(k1, qf[1][1], S1[sub], 0, 0, 0);
            }
            __builtin_amdgcn_s_setprio(0);

            if (ch == 1) {
                const int mrow0 = half * 128 + w4 * 16 + l16;
                const uint4 mwa = *(const uint4*)&Mb[buf][mrow0][0];
                const uint4 mwb = *(const uint4*)&Mb[buf][mrow0 + 64][0];
#pragma unroll
                for (int sub = 0; sub < 8; ++sub) {
                    const u32 sa = (sub >> 1) == 0 ? mwa.x : (sub >> 1) == 1 ? mwa.y
                                 : (sub >> 1) == 2 ? mwa.z : mwa.w;
                    const u32 sb = (sub >> 1) == 0 ? mwb.x : (sub >> 1) == 1 ? mwb.y
                                 : (sub >> 1) == 2 ? mwb.z : mwb.w;
#pragma unroll
                    for (int reg = 0; reg < 4; ++reg) {
                        const u32 bitp = (sub & 1) * 16 + quad * 4 + reg;
                        if (!((sa >> bitp) & 1u)) S0[sub][reg] = -1e30f;
                        if (!((sb >> bitp) & 1u)) S1[sub][reg] = -1e30f;
                    }
                }
            }

            // ---- lane-local softmax + packed b64 P-store (both s) ----
            float rs0 = 0.0f, rs1 = 0.0f;
#pragma unroll
            for (int sub = 0; sub < 8; ++sub) {
                float a0 = exp2f(S0[sub][0]);
                float a1 = exp2f(S0[sub][1]);
                float a2 = exp2f(S0[sub][2]);
                float a3 = exp2f(S0[sub][3]);
                rs0 += (a0 + a1) + (a2 + a3);
                ushort4 pk;
                pk.x = f2bf_trunc(a0); pk.y = f2bf_trunc(a1);
                pk.z = f2bf_trunc(a2); pk.w = f2bf_trunc(a3);
                *(ushort4*)&Ps[wave][l16 * PSTR + sub * 16 + quad * 4] = pk;
                float b0 = exp2f(S1[sub][0]);
                float b1 = exp2f(S1[sub][1]);
                float b2 = exp2f(S1[sub][2]);
                float b3 = exp2f(S1[sub][3]);
                rs1 += (b0 + b1) + (b2 + b3);
                ushort4 qk;
                qk.x = f2bf_trunc(b0); qk.y = f2bf_trunc(b1);
                qk.z = f2bf_trunc(b2); qk.w = f2bf_trunc(b3);
                *(ushort4*)&Ps[wave][(16 + l16) * PSTR + sub * 16 + quad * 4] = qk;
            }
            rs0 += __shfl_xor(rs0, 16);
            rs0 += __shfl_xor(rs0, 32);
            lq[0] += rs0;
            rs1 += __shfl_xor(rs1, 16);
            rs1 += __shfl_xor(rs1, 32);
            lq[1] += rs1;

            // ---- O += P V, both q-subtiles sharing the V reads ----
            short8 pa0[4], pa1[4];
#pragma unroll
            for (int ks = 0; ks < 4; ++ks) {
                pa0[ks] = *(const short8*)&Ps[wave][l16 * PSTR + ks * 32 + quad * 8];
                pa1[ks] = *(const short8*)&Ps[wave][(16 + l16) * PSTR + ks * 32 + quad * 8];
            }
            __builtin_amdgcn_s_setprio(1);
#pragma unroll
            for (int d = 0; d < 4; ++d) {
                const int row = d * 16 + l16;
#pragma unroll
                for (int ks = 0; ks < 4; ++ks) {
                    short8 vb = *(const short8*)&Vb[row * 128 + (((ks * 4 + quad) ^ l16) & 15) * 8];
                    O[0][d] = __builtin_amdgcn_mfma_f32_16x16x32_bf16(pa0[ks], vb, O[0][d], 0, 0, 0);
                    O[1][d] = __builtin_amdgcn_mfma_f32_16x16x32_bf16(pa1[ks], vb, O[1][d], 0, 0, 0);
                }
            }
            __builtin_amdgcn_s_setprio(0);
        }

        buf ^= 1;
        cur = nx;
    }

    // ---- redistribute per-query sums (lq lives at lane l16 = query) ----
    float dv[2][4];
#pragma unroll
    for (int s = 0; s < 2; ++s)
#pragma unroll
        for (int reg = 0; reg < 4; ++reg)
            dv[s][reg] = __shfl(lq[s], quad * 4 + reg);

    // ---- normalize + write into the consumed Q section ----
#pragma unroll
    for (int s = 0; s < 2; ++s) {
#pragma unroll
        for (int d = 0; d < 4; ++d) {
#pragma unroll
            for (int reg = 0; reg < 4; ++reg) {
                const int row = i0 + half * 128 + s * 64 + w4 * 16 + quad * 4 + reg;
                const int col = h * 64 + d * 16 + l16;
                Yout[((size_t)n * SEQ + row) * QS + col] = f2bf(O[s][d][reg] / dv[s][reg]);
            }
        }
    }
}

// ---------------------------------------------------------------------------
// Fused: LN( p0 + p1 + bias + resid ) -> fp32 out + optional bf16 out.
// ---------------------------------------------------------------------------
__global__ __launch_bounds__(256) void ln_fused2(const float* __restrict__ p0,
                                                 const float* __restrict__ p1,
                                                 const float* __restrict__ bias,
                                                 const float* __restrict__ resid,
                                                 const float* __restrict__ g,
                                                 const float* __restrict__ be,
                                                 float* __restrict__ Y,
                                                 u16* __restrict__ Yb) {
    const int row = blockIdx.x;
    const int t = threadIdx.x;
    __shared__ float red[256];

    const float4 a = ((const float4*)(p0 + (size_t)row * MD))[t];
    const float4 b = ((const float4*)(p1 + (size_t)row * MD))[t];
    const float4 r = ((const float4*)(resid + (size_t)row * MD))[t];
    const float4 bi = ((const float4*)bias)[t];
    float4 v;
    v.x = a.x + b.x + r.x + bi.x;
    v.y = a.y + b.y + r.y + bi.y;
    v.z = a.z + b.z + r.z + bi.z;
    v.w = a.w + b.w + r.w + bi.w;

    red[t] = v.x + v.y + v.z + v.w;
    __syncthreads();
    for (int s2 = 128; s2 > 0; s2 >>= 1) {
        if (t < s2) red[t] += red[t + s2];
        __syncthreads();
    }
    const float mu = red[0] * (1.0f / MD);
    __syncthreads();

    float dx = v.x - mu, dy = v.y - mu, dz = v.z - mu, dw = v.w - mu;
    red[t] = dx * dx + dy * dy + dz * dz + dw * dw;
    __syncthreads();
    for (int s2 = 128; s2 > 0; s2 >>= 1) {
        if (t < s2) red[t] += red[t + s2];
        __syncthreads();
    }
    const float var = red[0] * (1.0f / MD);
    const float rs = rsqrtf(var + EPSF);

    const float4 gv = ((const float4*)g)[t];
    const float4 bv = ((const float4*)be)[t];
    float4 o;
    o.x = dx * rs * gv.x + bv.x;
    o.y = dy * rs * gv.y + bv.y;
    o.z = dz * rs * gv.z + bv.z;
    o.w = dw * rs * gv.w + bv.w;
    if (Y) ((float4*)(Y + (size_t)row * MD))[t] = o;
    if (Yb) {
        ushort4 ob;
        ob.x = f2bf(o.x); ob.y = f2bf(o.y); ob.z = f2bf(o.z); ob.w = f2bf(o.w);
        ((ushort4*)(Yb + (size_t)row * MD))[t] = ob;
    }
}

// ---------------------------------------------------------------------------
// Workspace map (MB), liveness unchanged:
//   0-8    decb -> O2b -> Pcross(low) -> Hb
//   8-16   encb -> Pcross(high) -> Hb
//   16-32  weight repacks (dead after out-projs) -> Hb
//   32-40  W1T   40-48 W2T
//   48-72  QKVb -> O4b(48-56) -> FP1(48-64)
//   72-80  Vt
//   80-96  mcls/mbits (self-attn only) -> Tb = partial p0 (all split-K)
//   96-112 Pself == O2 == O4 (row-aligned aliasing, safe)
// ---------------------------------------------------------------------------
extern "C" void kernel_launch(void* const* d_in, const int* in_sizes, int n_in,
                              void* d_out, int out_size, void* d_ws, size_t ws_size,
                              hipStream_t stream) {
    const float* dec  = (const float*)d_in[0];
    const float* enc  = (const float*)d_in[1];
    const int*   mask = (const int*)d_in[2];
    const float* Wq_s = (const float*)d_in[3];
    const float* bq_s = (const float*)d_in[4];
    const float* Wk_s = (const float*)d_in[5];
    const float* bk_s = (const float*)d_in[6];
    const float* Wv_s = (const float*)d_in[7];
    const float* bv_s = (const float*)d_in[8];
    const float* Wo_s = (const float*)d_in[9];
    const float* bo_s = (const float*)d_in[10];
    const float* Wq_c = (const float*)d_in[11];
    const float* bq_c = (const float*)d_in[12];
    const float* Wk_c = (const float*)d_in[13];
    const float* bk_c = (const float*)d_in[14];
    const float* Wv_c = (const float*)d_in[15];
    const float* bv_c = (const float*)d_in[16];
    const float* Wo_c = (const float*)d_in[17];
    const float* bo_c = (const float*)d_in[18];
    const float* W1   = (const float*)d_in[19];
    const float* b1   = (const float*)d_in[20];
    const float* W2   = (const float*)d_in[21];
    const float* b2   = (const float*)d_in[22];
    const float* g1   = (const float*)d_in[23];
    const float* be1  = (const float*)d_in[24];
    const float* g2   = (const float*)d_in[25];
    const float* be2  = (const float*)d_in[26];
    const float* g3   = (const float*)d_in[27];
    const float* be3  = (const float*)d_in[28];

    char* wsb = (char*)d_ws;
    const size_t MB = 1u << 20;
    u16*   decb  = (u16*)(wsb + 0 * MB);
    u16*   O2b   = (u16*)(wsb + 0 * MB);
    u16*   encb  = (u16*)(wsb + 8 * MB);
    u16*   WqkvsT= (u16*)(wsb + 16 * MB);
    u16*   WqkvcT= (u16*)(wsb + 22 * MB);
    u16*   WosT  = (u16*)(wsb + 28 * MB);
    u16*   WocT  = (u16*)(wsb + 30 * MB);
    u16*   W1T   = (u16*)(wsb + 32 * MB);
    u16*   W2T   = (u16*)(wsb + 40 * MB);
    u16*   QKVb  = (u16*)(wsb + 48 * MB);
    u16*   O4b   = (u16*)(wsb + 48 * MB);
    u16*   Vt    = (u16*)(wsb + 72 * MB);
    u16*   Hb    = (u16*)(wsb + 0 * MB);
    int*   mcls  = (int*)(wsb + 80 * MB);
    u32*   mbits = (u32*)(wsb + 80 * MB + 64 * 1024);
    float* Tb    = (float*)(wsb + 80 * MB);
    float* Pself = (float*)(wsb + 96 * MB);
    float* Pcross= (float*)(wsb + 0 * MB);
    float* O2    = (float*)(wsb + 96 * MB);
    float* O4    = (float*)(wsb + 96 * MB);
    float* FP1   = (float*)(wsb + 48 * MB);

    dim3 blk(256);
    dim3 blk5(512);
    dim3 gConv(NK * MD / 4 / 256, 2);
    dim3 gMask(8, 8, 4);
    dim3 gQkvW(16, 16, 6);
    dim3 gFlatW(16, 16, 10);
    dim3 gAttn(SEQ / 256, NH, NB);
    dim3 gQKV(QS / 256, NK / 256);
    dim3 gOut(MD / 128, NK / 256, 2);
    dim3 gF1(FF / 256, NK / 256);
    dim3 gF2(MD / 128, NK / 256, 2);

    // ---- converts + repacks + mask precompute ----
    conv_bf16<<<gConv, blk, 0, stream>>>(dec, enc, decb, encb);
    mask_tiles<<<gMask, blk, 0, stream>>>(mask, mcls, mbits);

    QkvArgs qa;
    qa.src[0] = Wq_s; qa.src[1] = Wk_s; qa.src[2] = Wv_s;
    qa.src[3] = Wq_c; qa.src[4] = Wk_c; qa.src[5] = Wv_c;
    qa.dst[0] = WqkvsT;                 qa.dst[1] = WqkvsT + (size_t)1024 * 1024;
    qa.dst[2] = WqkvsT + (size_t)2048 * 1024;
    qa.dst[3] = WqkvcT;                 qa.dst[4] = WqkvcT + (size_t)1024 * 1024;
    qa.dst[5] = WqkvcT + (size_t)2048 * 1024;
    repack_qkv<<<gQkvW, blk, 0, stream>>>(qa);

    FlatArgs fa;
    fa.d[0] = { Wo_s, 1024, WosT, 1024 };
    fa.d[1] = { Wo_c, 1024, WocT, 1024 };
    for (int u = 0; u < 4; ++u)
        fa.d[2 + u] = { W1 + (size_t)u * 1024, 4096, W1T + (size_t)u * 1024 * 1024, 1024 };
    for (int u = 0; u < 4; ++u)
        fa.d[6 + u] = { W2 + (size_t)u * 1024 * 1024, 1024, W2T + (size_t)u * 1024, 4096 };
    repack_flat<<<gFlatW, blk, 0, stream>>>(fa);

    // ---- self attention ----
    gemm_256<0, 1, 1, 0><<<gQKV, blk5, 0, stream>>>(decb, decb, MD, WqkvsT, MD, bq_s, bk_s, bv_s, QKVb, Vt, MD, QS);
    attn_mfma<<<gAttn, blk5, 0, stream>>>(QKVb, Vt, mcls, mbits, QKVb);
    gemm_sk<<<gOut, blk5, 0, stream>>>(QKVb, QS, WosT, MD, Tb, Pself, MD / 2, MD);
    ln_fused2<<<NK, blk, 0, stream>>>(Tb, Pself, bo_s, dec, g1, be1, O2, O2b);

    // ---- cross attention ----
    gemm_256<0, 1, 1, 0><<<gQKV, blk5, 0, stream>>>(O2b, encb, MD, WqkvcT, MD, bq_c, bk_c, bv_c, QKVb, Vt, MD, QS);
    attn_mfma<<<gAttn, blk5, 0, stream>>>(QKVb, Vt, nullptr, nullptr, QKVb);
    gemm_sk<<<gOut, blk5, 0, stream>>>(QKVb, QS, WocT, MD, Tb, Pcross, MD / 2, MD);
    ln_fused2<<<NK, blk, 0, stream>>>(Tb, Pcross, bo_c, O2, g2, be2, O4, O4b);

    // ---- feed-forward (FFN1 on 256-tile C^T; FFN2 split-K=2 fused into LN) ----
    gemm_256<1, 0, 0, 1><<<gF1, blk5, 0, stream>>>(O4b, O4b, MD, W1T, MD, b1, nullptr, nullptr, Hb, nullptr, MD, FF);
    gemm_sk<<<gF2, blk5, 0, stream>>>(Hb, FF, W2T, FF, Tb, FP1, FF / 2, MD);
    ln_fused2<<<NK, blk, 0, stream>>>(Tb, FP1, b2, O4, g3, be3, (float*)d_out, nullptr);
}